// Round 9
// baseline (137.570 us; speedup 1.0000x reference)
//
#include <hip/hip_runtime.h>
#include <hip/hip_cooperative_groups.h>

namespace cg = cooperative_groups;

// X [B=8, L=4096, D=1024] fp32.  O = (L*X - colsum_over_L) / (L-1).
// Single cooperative kernel, all global traffic row-major contiguous
// (fill-kernel access pattern -> all HBM channels busy):
//   phase 1 : blocks read contiguous 256KB row-chunks, partial colsums -> ws
//   sync    : grid-wide
//   phase 1b: one wave per (b,d4): reduce 64 chunk partials -> C (32 KB)
//   sync    : grid-wide
//   phase 2 : contiguous grid-stride apply O = a*X + C  (X is L3-resident)
constexpr int Bn = 8;
constexpr int Ln = 4096;
constexpr int Dn = 1024;

constexpr int NB   = 256;                 // blocks (1 per CU, cooperative)
constexpr int NT   = 1024;                // threads per block
constexpr int D4   = Dn / 4;              // 256 f32x4 per row
constexpr int CHROWS = 64;                // rows per chunk
constexpr int NCHUNK = Bn * Ln / CHROWS;  // 512 chunks of 256 KB
constexpr size_t CH4 = (size_t)CHROWS * D4;        // 16384 f32x4 per chunk
constexpr size_t NV4 = (size_t)Bn * Ln * Dn / 4;   // 8388608 f32x4 total
constexpr size_t STRIDE4 = (size_t)NB * NT;        // 262144 -> 32 iters

typedef float f32x4 __attribute__((ext_vector_type(4)));

__global__ __launch_bounds__(NT) void ordering_coop_kernel(
    const float* __restrict__ X, float* __restrict__ O, float* __restrict__ WS) {
    f32x4* __restrict__ C4 = reinterpret_cast<f32x4*>(WS);      // 2048 f32x4
    f32x4* __restrict__ P4 = C4 + Bn * D4;                      // 512*256 f32x4
    const f32x4* __restrict__ X4 = reinterpret_cast<const f32x4*>(X);

    const int t   = threadIdx.x;
    const int bid = blockIdx.x;
    const int d4  = t & (D4 - 1);        // column quad 0..255
    const int rg  = t >> 8;              // row group 0..3

    cg::grid_group grid = cg::this_grid();
    __shared__ f32x4 lds[NT];            // 16 KiB

    // ---- Phase 1: two contiguous 256KB chunks per block ----
#pragma unroll
    for (int kk = 0; kk < 2; ++kk) {
        const int c = bid + NB * kk;     // chunk id 0..511
        const f32x4* __restrict__ Xc = X4 + (size_t)c * CH4;
        f32x4 a0 = (f32x4)0.f, a1 = (f32x4)0.f, a2 = (f32x4)0.f, a3 = (f32x4)0.f;
#pragma unroll
        for (int k = 0; k < 16; k += 4) {
            a0 += Xc[(size_t)((k + 0) * 4 + rg) * D4 + d4];
            a1 += Xc[(size_t)((k + 1) * 4 + rg) * D4 + d4];
            a2 += Xc[(size_t)((k + 2) * 4 + rg) * D4 + d4];
            a3 += Xc[(size_t)((k + 3) * 4 + rg) * D4 + d4];
        }
        lds[t] = (a0 + a1) + (a2 + a3);
        __syncthreads();
        if (t < D4) {
            const f32x4 s = (lds[t] + lds[t + 256]) + (lds[t + 512] + lds[t + 768]);
            P4[(size_t)c * D4 + t] = s;
        }
        __syncthreads();                 // lds reused next kk
    }
    grid.sync();

    // ---- Phase 1b: one wave per (b,d4) pair: reduce 64 chunk partials ----
    if (bid < 128) {
        const int w    = t >> 6;                 // wave 0..15
        const int lane = t & 63;
        const int p    = bid * 16 + w;           // pair 0..2047
        const int b    = p >> 8;
        const int dd   = p & (D4 - 1);
        f32x4 s = P4[(size_t)(b * 64 + lane) * D4 + dd];
#pragma unroll
        for (int m = 1; m <= 32; m <<= 1) {
            f32x4 o;
            o.x = __shfl_xor(s.x, m);
            o.y = __shfl_xor(s.y, m);
            o.z = __shfl_xor(s.z, m);
            o.w = __shfl_xor(s.w, m);
            s += o;
        }
        if (lane == 0) C4[p] = s * (-1.0f / (float)(Ln - 1));
    }
    grid.sync();

    // ---- Phase 2: contiguous grid-stride apply ----
    const float a = (float)Ln / (float)(Ln - 1);
    f32x4* __restrict__ O4 = reinterpret_cast<f32x4*>(O);
    const size_t gid = (size_t)bid * NT + t;
#pragma unroll 4
    for (size_t i = gid; i < NV4; i += STRIDE4) {
        const f32x4 c = C4[((i >> 20) << 8) | (i & (D4 - 1))];  // L2-resident
        O4[i] = a * X4[i] + c;
    }
}

extern "C" void kernel_launch(void* const* d_in, const int* in_sizes, int n_in,
                              void* d_out, int out_size, void* d_ws, size_t ws_size,
                              hipStream_t stream) {
    (void)in_sizes; (void)n_in; (void)ws_size; (void)out_size;
    const float* X = (const float*)d_in[0];
    float* O = (float*)d_out;
    float* WS = (float*)d_ws;   // 32 KB C + 2 MB partials

    void* args[] = {(void*)&X, (void*)&O, (void*)&WS};
    hipLaunchCooperativeKernel((const void*)ordering_coop_kernel,
                               dim3(NB), dim3(NT), args, 0, stream);
}

// Round 10
// 76.600 us; speedup vs baseline: 1.7960x; 1.7960x over previous
//
#include <hip/hip_runtime.h>

// X [B=8, L=4096, D=1024] fp32.  O = (L*X - colsum_over_L) / (L-1).
// Three plain kernels, ALL global accesses row-major contiguous:
//   K1 : 512 blocks, one 256KB row-chunk each (16KB contiguous per iter),
//        per-chunk column partials -> ws (2 MB). Pure streaming read.
//   K1b: one wave per (b,d4): shuffle-reduce 64 chunk partials -> C (32 KB).
//   K2 : contiguous streaming apply O = a*X + C; c hoisted (d fixed per thread).
constexpr int Bn = 8;
constexpr int Ln = 4096;
constexpr int Dn = 1024;
constexpr int D4 = Dn / 4;                 // 256 f32x4 per row

typedef float f32x4 __attribute__((ext_vector_type(4)));

// ---------------- K1: chunk partial colsums ----------------
constexpr int CHROWS = 64;                         // rows per chunk (256 KB)
constexpr int NCHUNK = Bn * Ln / CHROWS;           // 512 chunks
constexpr size_t CH4 = (size_t)CHROWS * D4;        // 16384 f32x4 per chunk

__global__ __launch_bounds__(1024) void colsum_part_kernel(
    const float* __restrict__ X, float* __restrict__ WS) {
    const f32x4* __restrict__ X4 = reinterpret_cast<const f32x4*>(X);
    f32x4* __restrict__ P4 = reinterpret_cast<f32x4*>(WS) + Bn * D4;

    const int t  = threadIdx.x;
    const int c  = blockIdx.x;          // chunk id
    const int d4 = t & (D4 - 1);        // column quad 0..255
    const int rg = t >> 8;              // row group 0..3

    const f32x4* __restrict__ Xc = X4 + (size_t)c * CH4;
    f32x4 a0 = (f32x4)0.f, a1 = (f32x4)0.f, a2 = (f32x4)0.f, a3 = (f32x4)0.f;
#pragma unroll
    for (int k = 0; k < 16; k += 4) {   // 4 rows (16 KB contiguous) per step
        a0 += Xc[(size_t)((k + 0) * 4 + rg) * D4 + d4];
        a1 += Xc[(size_t)((k + 1) * 4 + rg) * D4 + d4];
        a2 += Xc[(size_t)((k + 2) * 4 + rg) * D4 + d4];
        a3 += Xc[(size_t)((k + 3) * 4 + rg) * D4 + d4];
    }

    __shared__ f32x4 lds[1024];         // 16 KiB
    lds[t] = (a0 + a1) + (a2 + a3);
    __syncthreads();
    if (t < D4) {
        const f32x4 s = (lds[t] + lds[t + 256]) + (lds[t + 512] + lds[t + 768]);
        P4[(size_t)c * D4 + t] = s;
    }
}

// ---------------- K1b: reduce chunk partials -> C ----------------
__global__ __launch_bounds__(1024) void colsum_final_kernel(float* __restrict__ WS) {
    f32x4* __restrict__ C4 = reinterpret_cast<f32x4*>(WS);
    const f32x4* __restrict__ P4 = C4 + Bn * D4;

    const int w    = threadIdx.x >> 6;              // wave 0..15
    const int lane = threadIdx.x & 63;
    const int p    = blockIdx.x * 16 + w;           // (b,d4) pair 0..2047
    const int b    = p >> 8;
    const int dd   = p & (D4 - 1);

    f32x4 s = P4[(size_t)(b * 64 + lane) * D4 + dd];
#pragma unroll
    for (int m = 1; m <= 32; m <<= 1) {
        f32x4 o;
        o.x = __shfl_xor(s.x, m);
        o.y = __shfl_xor(s.y, m);
        o.z = __shfl_xor(s.z, m);
        o.w = __shfl_xor(s.w, m);
        s += o;
    }
    if (lane == 0) C4[p] = s * (-1.0f / (float)(Ln - 1));
}

// ---------------- K2: streaming apply ----------------
constexpr int AT   = 256;
constexpr int ABLK = 2048;
constexpr size_t STR4 = (size_t)ABLK * AT;          // 524288 (= D/4 aligned)

__global__ __launch_bounds__(AT) void apply_kernel(
    const float* __restrict__ X, const float* __restrict__ C,
    float* __restrict__ O) {
    const float a = (float)Ln / (float)(Ln - 1);
    const f32x4* __restrict__ X4 = reinterpret_cast<const f32x4*>(X);
    const f32x4* __restrict__ C4 = reinterpret_cast<const f32x4*>(C);
    f32x4* __restrict__ O4 = reinterpret_cast<f32x4*>(O);

    const size_t i0 = (size_t)blockIdx.x * AT + threadIdx.x;
    const int dd = (int)(i0 & (D4 - 1));            // column quad, loop-invariant
    // batch advances every 2 iterations (1M f32x4 per batch, stride 512K)
#pragma unroll
    for (int b = 0; b < Bn; ++b) {
        const f32x4 c = C4[(b << 8) | dd];          // L2-resident 32 KB
        const size_t i = i0 + (size_t)(2 * b) * STR4;
        O4[i]        = a * X4[i]        + c;
        O4[i + STR4] = a * X4[i + STR4] + c;
    }
}

extern "C" void kernel_launch(void* const* d_in, const int* in_sizes, int n_in,
                              void* d_out, int out_size, void* d_ws, size_t ws_size,
                              hipStream_t stream) {
    (void)in_sizes; (void)n_in; (void)ws_size; (void)out_size;
    const float* X = (const float*)d_in[0];
    float* O = (float*)d_out;
    float* WS = (float*)d_ws;          // 32 KB C + 2 MB partials

    colsum_part_kernel<<<NCHUNK, 1024, 0, stream>>>(X, WS);
    colsum_final_kernel<<<128, 1024, 0, stream>>>(WS);
    apply_kernel<<<ABLK, AT, 0, stream>>>(X, WS, O);
}

// Round 11
// 74.755 us; speedup vs baseline: 1.8403x; 1.0247x over previous
//
#include <hip/hip_runtime.h>

// X [B=8, L=4096, D=1024] fp32.  O = (L*X - colsum_over_L) / (L-1).
// Two kernels, all accesses contiguous (1KB per wave-instruction), and the
// apply kernel walks chunks in the SAME order as the sum kernel so the X
// re-read hits Infinity Cache (validated by R9's FETCH=132MB):
//   K1: block c sums its 256KB chunk (64 rows x D) -> P[c][256] (2MB ws)
//   K2: block c reduces its batch's 64 chunk-partials (redundant, ~64KB L3)
//       then applies O = a*X + c over chunk c, loads/stores interleaved.
constexpr int Bn = 8;
constexpr int Ln = 4096;
constexpr int Dn = 1024;
constexpr int D4 = Dn / 4;                  // 256 f32x4 per row

constexpr int CHROWS = 64;                  // rows per chunk (256 KB)
constexpr int NCHUNK = Bn * Ln / CHROWS;    // 512 chunks
constexpr int CPB    = Ln / CHROWS;         // 64 chunks per batch
constexpr size_t CH4 = (size_t)CHROWS * D4; // 16384 f32x4 per chunk

typedef float f32x4 __attribute__((ext_vector_type(4)));

// ---------------- K1: chunk partial colsums -> P ----------------
__global__ __launch_bounds__(1024) void k_sum(
    const float* __restrict__ X, float* __restrict__ WS) {
    const f32x4* __restrict__ X4 = reinterpret_cast<const f32x4*>(X);
    f32x4* __restrict__ P4 = reinterpret_cast<f32x4*>(WS);

    const int t  = threadIdx.x;
    const int c  = blockIdx.x;              // chunk id 0..511
    const int d4 = t & (D4 - 1);            // column quad 0..255
    const int rg = t >> 8;                  // row group 0..3

    const f32x4* __restrict__ Xc = X4 + (size_t)c * CH4;
    f32x4 a0 = (f32x4)0.f, a1 = (f32x4)0.f, a2 = (f32x4)0.f, a3 = (f32x4)0.f;
#pragma unroll
    for (int k = 0; k < 16; k += 4) {       // 4 rows (16 KB contiguous) per step
        a0 += Xc[(size_t)((k + 0) * 4 + rg) * D4 + d4];
        a1 += Xc[(size_t)((k + 1) * 4 + rg) * D4 + d4];
        a2 += Xc[(size_t)((k + 2) * 4 + rg) * D4 + d4];
        a3 += Xc[(size_t)((k + 3) * 4 + rg) * D4 + d4];
    }

    __shared__ f32x4 lds[1024];             // 16 KiB
    lds[t] = (a0 + a1) + (a2 + a3);
    __syncthreads();
    if (t < D4) {
        const f32x4 s = (lds[t] + lds[t + 256]) + (lds[t + 512] + lds[t + 768]);
        P4[(size_t)c * D4 + t] = s;         // contiguous 4 KB per block
    }
}

// ---------------- K2: per-block C reduce + streaming apply ----------------
__global__ __launch_bounds__(1024) void k_apply(
    const float* __restrict__ X, const float* __restrict__ WS,
    float* __restrict__ O) {
    const f32x4* __restrict__ X4 = reinterpret_cast<const f32x4*>(X);
    const f32x4* __restrict__ P4 = reinterpret_cast<const f32x4*>(WS);
    f32x4* __restrict__ O4 = reinterpret_cast<f32x4*>(O);

    const int t  = threadIdx.x;
    const int c  = blockIdx.x;              // chunk id 0..511 (same map as K1)
    const int b  = c / CPB;                 // batch of this chunk
    const int q  = t & (D4 - 1);            // column quad 0..255
    const int jg = t >> 8;                  // chunk sub-group 0..3

    // -- reduce 64 chunk partials of batch b (fixed order -> deterministic) --
    f32x4 s = (f32x4)0.f;
#pragma unroll
    for (int j = 0; j < 16; ++j) {          // 1 KB contiguous per wave-instr
        s += P4[(size_t)(b * CPB + jg * 16 + j) * D4 + q];
    }
    __shared__ f32x4 lds[1024];             // 16 KiB
    lds[t] = s;
    __syncthreads();
    if (t < D4) {
        const f32x4 tot = (lds[t] + lds[t + 256]) + (lds[t + 512] + lds[t + 768]);
        lds[t] = tot * (-1.0f / (float)(Ln - 1));
    }
    __syncthreads();
    const f32x4 cl = lds[q];                // loop-invariant per-column offset
    const float a = (float)Ln / (float)(Ln - 1);

    // -- apply over chunk c: same traversal order as K1 -> X hits L3 --
    const f32x4* __restrict__ Xc = X4 + (size_t)c * CH4;
    f32x4* __restrict__ Oc = O4 + (size_t)c * CH4;
#pragma unroll
    for (int k = 0; k < 16; ++k) {
        const size_t idx = (size_t)(k * 4 + jg) * D4 + q;
        Oc[idx] = a * Xc[idx] + cl;
    }
}

extern "C" void kernel_launch(void* const* d_in, const int* in_sizes, int n_in,
                              void* d_out, int out_size, void* d_ws, size_t ws_size,
                              hipStream_t stream) {
    (void)in_sizes; (void)n_in; (void)ws_size; (void)out_size;
    const float* X = (const float*)d_in[0];
    float* O = (float*)d_out;
    float* WS = (float*)d_ws;               // 2 MB of chunk partials

    k_sum<<<NCHUNK, 1024, 0, stream>>>(X, WS);
    k_apply<<<NCHUNK, 1024, 0, stream>>>(X, WS, O);
}